// Round 8
// baseline (546.498 us; speedup 1.0000x reference)
//
#include <hip/hip_runtime.h>

// ShiftWindowMSA (Swin) fused kernels for MI355X (gfx950).
// B=16, H=W=64, C=512, NH=16, hd=32, WS=8, SS=4 -> 1024 windows x 64 tokens.
//
// R8 = R7 with one lever: occupancy 2 -> 3 waves/SIMD on k_qa and k_proj2.
//  - R7 measured: k_qa FETCH 39 MB (4-blocks/window L2 schedule CONFIRMED),
//    WRITE 65 MB (no spill), but Occ 22.5% / MfmaUtil 13.8% -> latency-bound.
//  - k_qa now 2-pass QKV (q/k then v, R6-proven code, peak acc 64 regs) and
//    __launch_bounds__(256,3): est. peak live ~112 regs < 170 budget.
//    LDS 49152*3 = 144 KB <= 160 KB. L2/XCD: 24 win * 64 KB + 1.5 MB w < 4 MB.
//  - Controlled retest of (256,3): R2's catastrophe had 96 live acc; spill
//    signature = VGPR<=90 AND WRITE >> 65 MB. If seen, rule hardens.
//  - k_proj2 -> (256,3) too (peak ~120 regs, LDS 0; yw overflow -> L3).
// Tier B fallback (ws >= 66 MiB): R1 proven path.

typedef short  short8  __attribute__((ext_vector_type(8)));
typedef short  short4v __attribute__((ext_vector_type(4)));
typedef float  floatx4 __attribute__((ext_vector_type(4)));

#define DEVI static __device__ __forceinline__

DEVI unsigned short f2bf(float f) {
    union { float f; unsigned int u; } v;
    v.f = f;
    return (unsigned short)((v.u + 0x7fffu + ((v.u >> 16) & 1u)) >> 16);
}

// ---------------------------------------------------------------------------
// wcvt: qkv_w (1536x512) then proj_w (512x512) fp32 -> bf16 into wbf.
// ---------------------------------------------------------------------------
__global__ void wcvt(const float* __restrict__ qkv_w,
                     const float* __restrict__ proj_w,
                     unsigned short* __restrict__ wbf) {
    const int idx = ((blockIdx.x << 8) + threadIdx.x) << 2;
    const float* src = (idx < 786432) ? (qkv_w + idx) : (proj_w + (idx - 786432));
    const floatx4 v = *(const floatx4*)src;
    short4v o;
    o[0] = (short)f2bf(v[0]); o[1] = (short)f2bf(v[1]);
    o[2] = (short)f2bf(v[2]); o[3] = (short)f2bf(v[3]);
    *(short4v*)(wbf + idx) = o;
}

// ---------------------------------------------------------------------------
// xcvt: gather cyclic-shifted windows of query -> xw bf16 [win][kc][tok][32].
// Grid 16384; window w handled by blocks with bid%8 == w/128 (XCD grouping).
// ---------------------------------------------------------------------------
__global__ void xcvt(const float* __restrict__ query,
                     unsigned short* __restrict__ xw) {
    const int bid = blockIdx.x;
    const int x   = bid & 7;
    const int s   = bid >> 3;                           // 0..2047
    const int win = (x << 7) + (s >> 4);
    const int rem = ((s & 15) << 8) + threadIdx.x;      // 0..4095
    const int jc  = rem & 3;                            // 8-short chunk in 32
    const int tok = (rem >> 2) & 63;
    const int kc  = rem >> 8;                           // 0..15
    const int b   = win >> 6, wy = (win >> 3) & 7, wx = win & 7;
    const int ty  = tok >> 3, tx = tok & 7;
    const int gh  = ((wy << 3) + ty + 4) & 63;
    const int gw  = ((wx << 3) + tx + 4) & 63;
    const float* src = query + (((b << 12) + (gh << 6) + gw) << 9) + (kc << 5) + (jc << 3);
    const floatx4 v0 = *(const floatx4*)src;
    const floatx4 v1 = *(const floatx4*)(src + 4);
    short8 sv;
    sv[0] = (short)f2bf(v0[0]); sv[1] = (short)f2bf(v0[1]);
    sv[2] = (short)f2bf(v0[2]); sv[3] = (short)f2bf(v0[3]);
    sv[4] = (short)f2bf(v1[0]); sv[5] = (short)f2bf(v1[1]);
    sv[6] = (short)f2bf(v1[2]); sv[7] = (short)f2bf(v1[3]);
    *(short8*)(xw + (win << 15) + (kc << 11) + (tok << 5) + (jc << 3)) = sv;
}

// ---------------------------------------------------------------------------
// k_qa: grid 4096 = (window, head-chunk). 4 waves/block, wave = head
// h = hc*4+wave. 2-pass QKV GEMM (q/k then v; window L2-hot, read twice) ->
// q/k/vT staged to wave-private swizzled LDS -> QK^T -> softmax -> PV ->
// y head-tile (2 KB) to yw. No barriers.
// ---------------------------------------------------------------------------
__global__ __launch_bounds__(256, 3)
void k_qa(const unsigned short* __restrict__ wbf,
          const unsigned short* __restrict__ xw,
          unsigned short* __restrict__ yw,
          const float* __restrict__ qkv_b,
          const float* __restrict__ bias_table)
{
    __shared__ __align__(16) unsigned short smem[24576];   // 4 waves * 6144

    const int tid  = threadIdx.x;
    const int lane = tid & 63;
    const int l15  = lane & 15;
    const int quad = lane >> 4;
    const int wave = tid >> 6;

    const int bid = blockIdx.x;
    const int x   = bid & 7;
    const int s   = bid >> 3;                           // 0..511
    const int win = (x << 7) + (s >> 2);
    const int hc  = s & 3;
    const int h   = (hc << 2) + wave;

    const int wy  = (win >> 3) & 7;
    const int wx  = win & 7;
    const int mid = ((wy == 7) ? 2 : 0) | ((wx == 7) ? 1 : 0);

    unsigned short* wbs = smem + wave * 6144;
    unsigned short* qbf = wbs;                          // [64][32] swizzled
    unsigned short* kbf = wbs + 2048;                   // [64][32] swizzled
    unsigned short* vT  = wbs + 4096;                   // [32][64] swizzled
    unsigned short* pbf = wbs;                          // [64][64] swizzled, overlays q+k

    const int sw4 = (l15 & 3) ^ (l15 >> 2);             // q/k read swizzle
    const int sw8 = (l15 & 7) ^ (l15 >> 3);             // vT/p read swizzle

    const unsigned short* xa = xw + (win << 15) + (l15 << 5) + (quad << 3);
    const float scale = 0.17677669529663687f;           // 1/sqrt(32)
    const floatx4 fz = {0.f, 0.f, 0.f, 0.f};

    // ---------------- pass 1: q,k projection (acc = 64 regs) ----------------
    {
        floatx4 accq[4][2], acck[4][2];
        #pragma unroll
        for (int mt = 0; mt < 4; ++mt)
            #pragma unroll
            for (int nt = 0; nt < 2; ++nt) { accq[mt][nt] = fz; acck[mt][nt] = fz; }

        const unsigned short* wq = wbf + ((h << 5) + l15) * 512 + (quad << 3);
        const unsigned short* wk = wq + 262144;

        #pragma unroll 2
        for (int kk = 0; kk < 512; kk += 32) {
            short8 a[4], bq[2], bk2[2];
            #pragma unroll
            for (int mt = 0; mt < 4; ++mt)
                a[mt] = *(const short8*)(xa + (kk << 6) + (mt << 9));
            #pragma unroll
            for (int nt = 0; nt < 2; ++nt) {
                const int ro = (nt << 4) * 512 + kk;
                bq[nt]  = *(const short8*)(wq + ro);
                bk2[nt] = *(const short8*)(wk + ro);
            }
            #pragma unroll
            for (int nt = 0; nt < 2; ++nt)
                #pragma unroll
                for (int mt = 0; mt < 4; ++mt) {
                    accq[mt][nt] = __builtin_amdgcn_mfma_f32_16x16x32_bf16(a[mt], bq[nt],  accq[mt][nt], 0, 0, 0);
                    acck[mt][nt] = __builtin_amdgcn_mfma_f32_16x16x32_bf16(a[mt], bk2[nt], acck[mt][nt], 0, 0, 0);
                }
        }

        // bias + stage q,k into swizzled LDS
        #pragma unroll
        for (int nt = 0; nt < 2; ++nt) {
            const int cix = (h << 5) + (nt << 4) + l15;
            const float bq_ = qkv_b[cix];
            const float bk_ = qkv_b[512 + cix];
            #pragma unroll
            for (int mt = 0; mt < 4; ++mt)
                #pragma unroll
                for (int r = 0; r < 4; ++r) {
                    const int row = (mt << 4) + (quad << 2) + r;
                    const int ph  = (2 * nt + (l15 >> 3)) ^ (row & 3) ^ ((row >> 2) & 3);
                    const int off = (row << 5) + (l15 & 7) + (ph << 3);
                    qbf[off] = f2bf(accq[mt][nt][r] + bq_);
                    kbf[off] = f2bf(acck[mt][nt][r] + bk_);
                }
        }
    }

    // ---------------- pass 2: v projection (acc = 32 regs) ------------------
    {
        floatx4 accv[4][2];
        #pragma unroll
        for (int mt = 0; mt < 4; ++mt)
            #pragma unroll
            for (int nt = 0; nt < 2; ++nt) accv[mt][nt] = fz;

        const unsigned short* wv = wbf + 524288 + ((h << 5) + l15) * 512 + (quad << 3);

        #pragma unroll 2
        for (int kk = 0; kk < 512; kk += 32) {
            short8 a[4], bv2[2];
            #pragma unroll
            for (int mt = 0; mt < 4; ++mt)
                a[mt] = *(const short8*)(xa + (kk << 6) + (mt << 9));
            #pragma unroll
            for (int nt = 0; nt < 2; ++nt)
                bv2[nt] = *(const short8*)(wv + (nt << 4) * 512 + kk);
            #pragma unroll
            for (int nt = 0; nt < 2; ++nt)
                #pragma unroll
                for (int mt = 0; mt < 4; ++mt)
                    accv[mt][nt] = __builtin_amdgcn_mfma_f32_16x16x32_bf16(a[mt], bv2[nt], accv[mt][nt], 0, 0, 0);
        }

        // bias + stage v transposed into swizzled LDS
        #pragma unroll
        for (int nt = 0; nt < 2; ++nt) {
            const float bv_ = qkv_b[1024 + (h << 5) + (nt << 4) + l15];
            #pragma unroll
            for (int mt = 0; mt < 4; ++mt) {
                short4v vv;
                #pragma unroll
                for (int r = 0; r < 4; ++r)
                    vv[r] = (short)f2bf(accv[mt][nt][r] + bv_);
                const int vph = (2 * mt + (quad >> 1)) ^ sw8;
                *(short4v*)&vT[(((nt << 4) + l15) << 6) + ((quad & 1) << 2) + (vph << 3)] = vv;
            }
        }
    }
    // (no barrier: scratch is wave-private)

    // ---------------- Q K^T --------------------------------------------------
    short8 qa[4], ka[4];
    #pragma unroll
    for (int t = 0; t < 4; ++t) {
        const int off = ((((t << 4) + l15)) << 5) + ((quad ^ sw4) << 3);
        qa[t] = *(const short8*)&qbf[off];
        ka[t] = *(const short8*)&kbf[off];
    }
    floatx4 s4[4][4];
    #pragma unroll
    for (int mt = 0; mt < 4; ++mt)
        #pragma unroll
        for (int nt = 0; nt < 4; ++nt)
            s4[mt][nt] = __builtin_amdgcn_mfma_f32_16x16x32_bf16(qa[mt], ka[nt], fz, 0, 0, 0);

    // ------- logits: scale + rel-pos bias (closed-form idx) + shift mask -----
    int  gjv[4]; bool jrow[4], jcol[4];
    #pragma unroll
    for (int nt = 0; nt < 4; ++nt) {
        const int j  = (nt << 4) + l15;
        const int j2 = 63 - j;
        gjv[nt]  = 15 * (j2 >> 3) + (j2 & 7);
        jrow[nt] = (j >> 3) < 4;
        jcol[nt] = (j & 7) < 4;
    }
    #pragma unroll
    for (int mt = 0; mt < 4; ++mt) {
        const int i0  = (mt << 4) + (quad << 2);
        const int fi0 = 15 * (i0 >> 3) + (i0 & 7);
        const bool irow = (i0 >> 3) < 4;
        const bool icol = (i0 & 7) == 0;
        #pragma unroll
        for (int nt = 0; nt < 4; ++nt) {
            float mval = 0.0f;
            if ((mid & 2) && (irow != jrow[nt])) mval = -100.0f;
            if ((mid & 1) && (icol != jcol[nt])) mval = -100.0f;
            const float* bp = bias_table + (fi0 + gjv[nt]) * 16 + h;
            #pragma unroll
            for (int r = 0; r < 4; ++r)
                s4[mt][nt][r] = s4[mt][nt][r] * scale + bp[r * 16] + mval;
        }
    }

    // ---- softmax (max-subtracted, normalized) -> P in swizzled LDS ----------
    #pragma unroll
    for (int mt = 0; mt < 4; ++mt)
        #pragma unroll
        for (int r = 0; r < 4; ++r) {
            float m = fmaxf(fmaxf(s4[mt][0][r], s4[mt][1][r]),
                            fmaxf(s4[mt][2][r], s4[mt][3][r]));
            m = fmaxf(m, __shfl_xor(m, 1));
            m = fmaxf(m, __shfl_xor(m, 2));
            m = fmaxf(m, __shfl_xor(m, 4));
            m = fmaxf(m, __shfl_xor(m, 8));
            float loc = 0.0f;
            #pragma unroll
            for (int nt = 0; nt < 4; ++nt) {
                s4[mt][nt][r] = __expf(s4[mt][nt][r] - m);
                loc += s4[mt][nt][r];
            }
            loc += __shfl_xor(loc, 1);
            loc += __shfl_xor(loc, 2);
            loc += __shfl_xor(loc, 4);
            loc += __shfl_xor(loc, 8);
            const float inv = 1.0f / loc;               // loc >= 1 (max entry = 1)
            const int row = (mt << 4) + (quad << 2) + r;
            #pragma unroll
            for (int nt = 0; nt < 4; ++nt) {
                const int ph = (2 * nt + (l15 >> 3)) ^ (row & 7) ^ ((row >> 3) & 1);
                pbf[(row << 6) + (l15 & 7) + (ph << 3)] = f2bf(s4[mt][nt][r] * inv);
            }
        }
    // (no barrier: pbf is wave-private)

    // ---------------- P V -> y head-tile to global yw ------------------------
    short8 pa[4][2], va[2][2];
    #pragma unroll
    for (int mt = 0; mt < 4; ++mt)
        #pragma unroll
        for (int ks = 0; ks < 2; ++ks)
            pa[mt][ks] = *(const short8*)&pbf[((((mt << 4) + l15)) << 6) + ((((ks << 2) + quad) ^ sw8) << 3)];
    #pragma unroll
    for (int nt = 0; nt < 2; ++nt)
        #pragma unroll
        for (int ks = 0; ks < 2; ++ks)
            va[nt][ks] = *(const short8*)&vT[((((nt << 4) + l15)) << 6) + ((((ks << 2) + quad) ^ sw8) << 3)];

    unsigned short* yh = yw + (win << 15) + (h << 11);
    #pragma unroll
    for (int mt = 0; mt < 4; ++mt)
        #pragma unroll
        for (int nt = 0; nt < 2; ++nt) {
            floatx4 acc = fz;
            acc = __builtin_amdgcn_mfma_f32_16x16x32_bf16(pa[mt][0], va[nt][0], acc, 0, 0, 0);
            acc = __builtin_amdgcn_mfma_f32_16x16x32_bf16(pa[mt][1], va[nt][1], acc, 0, 0, 0);
            #pragma unroll
            for (int r = 0; r < 4; ++r) {
                const int tok = (mt << 4) + (quad << 2) + r;
                yh[(tok << 5) + (nt << 4) + l15] = f2bf(acc[r]);
            }
        }
}

// ---------------------------------------------------------------------------
// k_proj2: proj GEMM, token-split. Grid 1024 (1 block = 1 window); wave =
// 32 tok x 128 out-ch per pass (2 passes) -> acc[2][8]. (256,3) for occupancy.
// Window-reverse + reverse cyclic shift folded into the output scatter.
// ---------------------------------------------------------------------------
__global__ __launch_bounds__(256, 3)
void k_proj2(const unsigned short* __restrict__ wbf,
             const unsigned short* __restrict__ yw,
             const float* __restrict__ proj_b,
             float* __restrict__ out)
{
    const int tid  = threadIdx.x;
    const int lane = tid & 63;
    const int l15  = lane & 15;
    const int quad = lane >> 4;
    const int wave = tid >> 6;
    const int th   = wave & 1;                          // token half
    const int cq   = wave >> 1;                         // channel 128-half

    const int bid = blockIdx.x;
    const int x   = bid & 7;
    const int s   = bid >> 3;
    const int win = (x << 7) + s;
    const int b   = win >> 6;
    const int wy  = (win >> 3) & 7;
    const int wx  = win & 7;

    const unsigned short* ya  = yw + (win << 15) + (l15 << 5) + (quad << 3);
    const unsigned short* pwb = wbf + 786432;           // proj_w bf16
    const floatx4 fz = {0.f, 0.f, 0.f, 0.f};

    for (int pass = 0; pass < 2; ++pass) {
        const int co0 = (pass << 8) + (cq << 7);
        floatx4 acc[2][8];
        #pragma unroll
        for (int mt = 0; mt < 2; ++mt)
            #pragma unroll
            for (int nt = 0; nt < 8; ++nt) acc[mt][nt] = fz;

        const unsigned short* wp = pwb + (co0 + l15) * 512 + (quad << 3);

        #pragma unroll 2
        for (int kk = 0; kk < 512; kk += 32) {
            short8 a[2], bfr[8];
            #pragma unroll
            for (int mt = 0; mt < 2; ++mt)
                a[mt] = *(const short8*)(ya + (kk << 6) + (((th << 1) + mt) << 9));
            #pragma unroll
            for (int nt = 0; nt < 8; ++nt)
                bfr[nt] = *(const short8*)(wp + (nt << 4) * 512 + kk);
            #pragma unroll
            for (int nt = 0; nt < 8; ++nt)
                #pragma unroll
                for (int mt = 0; mt < 2; ++mt)
                    acc[mt][nt] = __builtin_amdgcn_mfma_f32_16x16x32_bf16(a[mt], bfr[nt], acc[mt][nt], 0, 0, 0);
        }

        #pragma unroll
        for (int nt = 0; nt < 8; ++nt) {
            const float pb_ = proj_b[co0 + (nt << 4) + l15];
            #pragma unroll
            for (int mt = 0; mt < 2; ++mt)
                #pragma unroll
                for (int r = 0; r < 4; ++r) {
                    const int tok = (((th << 1) + mt) << 4) + (quad << 2) + r;
                    const int ty = tok >> 3, tx = tok & 7;
                    const int gh = ((wy << 3) + ty + 4) & 63;
                    const int gw = ((wx << 3) + tx + 4) & 63;
                    out[(((b << 12) + (gh << 6) + gw) << 9) + co0 + (nt << 4) + l15] =
                        acc[mt][nt][r] + pb_;
                }
        }
    }
}

// ---------------------------------------------------------------------------
// Tier B fallback: R1's proven fused kernel (QKV+attn+proj from pre-tiled xw).
// ---------------------------------------------------------------------------
__global__ __launch_bounds__(256, 2)
void k_fused_r1(const unsigned short* __restrict__ wbf,
                const unsigned short* __restrict__ xw,
                const float* __restrict__ qkv_b,
                const float* __restrict__ proj_b,
                const float* __restrict__ bias_table,
                float* __restrict__ out)
{
    __shared__ __align__(16) unsigned short smem[33280];

    const int tid  = threadIdx.x;
    const int lane = tid & 63;
    const int l15  = lane & 15;
    const int quad = lane >> 4;
    const int wave = tid >> 6;

    const int win = blockIdx.x;
    const int b   = win >> 6;
    const int wy  = (win >> 3) & 7;
    const int wx  = win & 7;
    const int mid = ((wy == 7) ? 2 : 0) | ((wx == 7) ? 1 : 0);

    unsigned short* xs  = smem;
    unsigned short* wb  = smem + wave * 7424;
    unsigned short* qbf = wb;
    unsigned short* kbf = wb + 2560;
    unsigned short* vT  = wb + 5120;
    unsigned short* pbf = wb;

    const unsigned short* xa = xw + (win << 15) + (l15 << 5) + (quad << 3);
    const float scale = 0.17677669529663687f;
    const floatx4 fz = {0.f, 0.f, 0.f, 0.f};
    unsigned int po[4][16];

    for (int hh = 0; hh < 4; ++hh) {
        const int h = (wave << 2) + hh;
        floatx4 accq[4][2], acck[4][2], accv[4][2];
        #pragma unroll
        for (int mt = 0; mt < 4; ++mt)
            #pragma unroll
            for (int nt = 0; nt < 2; ++nt) { accq[mt][nt] = fz; acck[mt][nt] = fz; accv[mt][nt] = fz; }

        const unsigned short* wq = wbf + ((h << 5) + l15) * 512 + (quad << 3);
        const unsigned short* wk = wq + 512 * 512;
        const unsigned short* wv = wk + 512 * 512;

        #pragma unroll 2
        for (int kk = 0; kk < 512; kk += 32) {
            short8 a[4], bq[2], bk2[2], bv2[2];
            #pragma unroll
            for (int mt = 0; mt < 4; ++mt)
                a[mt] = *(const short8*)(xa + (kk << 6) + (mt << 9));
            #pragma unroll
            for (int nt = 0; nt < 2; ++nt) {
                const int ro = (nt << 4) * 512 + kk;
                bq[nt]  = *(const short8*)(wq + ro);
                bk2[nt] = *(const short8*)(wk + ro);
                bv2[nt] = *(const short8*)(wv + ro);
            }
            #pragma unroll
            for (int nt = 0; nt < 2; ++nt)
                #pragma unroll
                for (int mt = 0; mt < 4; ++mt) {
                    accq[mt][nt] = __builtin_amdgcn_mfma_f32_16x16x32_bf16(a[mt], bq[nt],  accq[mt][nt], 0, 0, 0);
                    acck[mt][nt] = __builtin_amdgcn_mfma_f32_16x16x32_bf16(a[mt], bk2[nt], acck[mt][nt], 0, 0, 0);
                    accv[mt][nt] = __builtin_amdgcn_mfma_f32_16x16x32_bf16(a[mt], bv2[nt], accv[mt][nt], 0, 0, 0);
                }
        }

        #pragma unroll
        for (int nt = 0; nt < 2; ++nt) {
            const int cix = (h << 5) + (nt << 4) + l15;
            const float bq_ = qkv_b[cix];
            const float bk_ = qkv_b[512 + cix];
            const float bv_ = qkv_b[1024 + cix];
            #pragma unroll
            for (int mt = 0; mt < 4; ++mt) {
                short4v vv;
                #pragma unroll
                for (int r = 0; r < 4; ++r) {
                    const int row = (mt << 4) + (quad << 2) + r;
                    qbf[row * 40 + (nt << 4) + l15] = f2bf(accq[mt][nt][r] + bq_);
                    kbf[row * 40 + (nt << 4) + l15] = f2bf(acck[mt][nt][r] + bk_);
                    vv[r] = (short)f2bf(accv[mt][nt][r] + bv_);
                }
                *(short4v*)&vT[((nt << 4) + l15) * 72 + (mt << 4) + (quad << 2)] = vv;
            }
        }

        short8 qa[4], ka[4];
        #pragma unroll
        for (int t = 0; t < 4; ++t) {
            qa[t] = *(const short8*)&qbf[((t << 4) + l15) * 40 + (quad << 3)];
            ka[t] = *(const short8*)&kbf[((t << 4) + l15) * 40 + (quad << 3)];
        }
        floatx4 s4[4][4];
        #pragma unroll
        for (int mt = 0; mt < 4; ++mt)
            #pragma unroll
            for (int nt = 0; nt < 4; ++nt)
                s4[mt][nt] = __builtin_amdgcn_mfma_f32_16x16x32_bf16(qa[mt], ka[nt], fz, 0, 0, 0);

        int  gjv[4]; bool jrow[4], jcol[4];
        #pragma unroll
        for (int nt = 0; nt < 4; ++nt) {
            const int j  = (nt << 4) + l15;
            const int j2 = 63 - j;
            gjv[nt]  = 15 * (j2 >> 3) + (j2 & 7);
            jrow[nt] = (j >> 3) < 4;
            jcol[nt] = (j & 7) < 4;
        }
        #pragma unroll
        for (int mt = 0; mt < 4; ++mt) {
            const int i0  = (mt << 4) + (quad << 2);
            const int fi0 = 15 * (i0 >> 3) + (i0 & 7);
            const bool irow = (i0 >> 3) < 4;
            const bool icol = (i0 & 7) == 0;
            #pragma unroll
            for (int nt = 0; nt < 4; ++nt) {
                float mval = 0.0f;
                if ((mid & 2) && (irow != jrow[nt])) mval = -100.0f;
                if ((mid & 1) && (icol != jcol[nt])) mval = -100.0f;
                const float* bp = bias_table + (fi0 + gjv[nt]) * 16 + h;
                #pragma unroll
                for (int r = 0; r < 4; ++r)
                    s4[mt][nt][r] = s4[mt][nt][r] * scale + bp[r * 16] + mval;
            }
        }

        #pragma unroll
        for (int mt = 0; mt < 4; ++mt)
            #pragma unroll
            for (int r = 0; r < 4; ++r) {
                float m = fmaxf(fmaxf(s4[mt][0][r], s4[mt][1][r]),
                                fmaxf(s4[mt][2][r], s4[mt][3][r]));
                m = fmaxf(m, __shfl_xor(m, 1));
                m = fmaxf(m, __shfl_xor(m, 2));
                m = fmaxf(m, __shfl_xor(m, 4));
                m = fmaxf(m, __shfl_xor(m, 8));
                float loc = 0.0f;
                #pragma unroll
                for (int nt = 0; nt < 4; ++nt) {
                    s4[mt][nt][r] = __expf(s4[mt][nt][r] - m);
                    loc += s4[mt][nt][r];
                }
                loc += __shfl_xor(loc, 1);
                loc += __shfl_xor(loc, 2);
                loc += __shfl_xor(loc, 4);
                loc += __shfl_xor(loc, 8);
                const float inv = 1.0f / loc;
                const int row = (mt << 4) + (quad << 2) + r;
                #pragma unroll
                for (int nt = 0; nt < 4; ++nt)
                    pbf[row * 72 + (nt << 4) + l15] = f2bf(s4[mt][nt][r] * inv);
            }

        short8 pa[4][2], va[2][2];
        #pragma unroll
        for (int mt = 0; mt < 4; ++mt)
            #pragma unroll
            for (int ks = 0; ks < 2; ++ks)
                pa[mt][ks] = *(const short8*)&pbf[((mt << 4) + l15) * 72 + (ks << 5) + (quad << 3)];
        #pragma unroll
        for (int nt = 0; nt < 2; ++nt)
            #pragma unroll
            for (int ks = 0; ks < 2; ++ks)
                va[nt][ks] = *(const short8*)&vT[((nt << 4) + l15) * 72 + (ks << 5) + (quad << 3)];

        #pragma unroll
        for (int mt = 0; mt < 4; ++mt)
            #pragma unroll
            for (int nt = 0; nt < 2; ++nt) {
                floatx4 acc = fz;
                acc = __builtin_amdgcn_mfma_f32_16x16x32_bf16(pa[mt][0], va[nt][0], acc, 0, 0, 0);
                acc = __builtin_amdgcn_mfma_f32_16x16x32_bf16(pa[mt][1], va[nt][1], acc, 0, 0, 0);
                const int pi = ((mt << 1) + nt) << 1;
                po[hh][pi]     = (unsigned int)f2bf(acc[0]) | ((unsigned int)f2bf(acc[1]) << 16);
                po[hh][pi + 1] = (unsigned int)f2bf(acc[2]) | ((unsigned int)f2bf(acc[3]) << 16);
            }
    }
    __syncthreads();

    #pragma unroll
    for (int hh = 0; hh < 4; ++hh) {
        const int ch0 = (((wave << 2) + hh) << 5) + l15;
        #pragma unroll
        for (int mt = 0; mt < 4; ++mt)
            #pragma unroll
            for (int nt = 0; nt < 2; ++nt) {
                const int pi = ((mt << 1) + nt) << 1;
                #pragma unroll
                for (int r = 0; r < 4; ++r) {
                    const int row = (mt << 4) + (quad << 2) + r;
                    const unsigned int w = po[hh][pi + (r >> 1)];
                    xs[row * 520 + ch0 + (nt << 4)] =
                        (unsigned short)((w >> ((r & 1) << 4)) & 0xffffu);
                }
            }
    }
    __syncthreads();

    const unsigned short* pwb = wbf + 786432;
    for (int pass = 0; pass < 2; ++pass) {
        const int co0 = (wave << 7) + (pass << 6);
        floatx4 acc[4][4];
        #pragma unroll
        for (int mt = 0; mt < 4; ++mt)
            #pragma unroll
            for (int nt = 0; nt < 4; ++nt) acc[mt][nt] = fz;

        const unsigned short* wp = pwb + (co0 + l15) * 512 + (quad << 3);

        #pragma unroll 2
        for (int kk = 0; kk < 512; kk += 32) {
            short8 a[4], bfr[4];
            #pragma unroll
            for (int mt = 0; mt < 4; ++mt)
                a[mt] = *(const short8*)&xs[((mt << 4) + l15) * 520 + kk + (quad << 3)];
            #pragma unroll
            for (int nt = 0; nt < 4; ++nt)
                bfr[nt] = *(const short8*)(wp + (nt << 4) * 512 + kk);
            #pragma unroll
            for (int nt = 0; nt < 4; ++nt)
                #pragma unroll
                for (int mt = 0; mt < 4; ++mt)
                    acc[mt][nt] = __builtin_amdgcn_mfma_f32_16x16x32_bf16(a[mt], bfr[nt], acc[mt][nt], 0, 0, 0);
        }

        #pragma unroll
        for (int nt = 0; nt < 4; ++nt) {
            const float pb_ = proj_b[co0 + (nt << 4) + l15];
            #pragma unroll
            for (int mt = 0; mt < 4; ++mt)
                #pragma unroll
                for (int r = 0; r < 4; ++r) {
                    const int tok = (mt << 4) + (quad << 2) + r;
                    const int ty = tok >> 3, tx = tok & 7;
                    const int gh = ((wy << 3) + ty + 4) & 63;
                    const int gw = ((wx << 3) + tx + 4) & 63;
                    out[(((b << 12) + (gh << 6) + gw) << 9) + co0 + (nt << 4) + l15] =
                        acc[mt][nt][r] + pb_;
                }
        }
    }
}

// ---------------------------------------------------------------------------
extern "C" void kernel_launch(void* const* d_in, const int* in_sizes, int n_in,
                              void* d_out, int out_size, void* d_ws, size_t ws_size,
                              hipStream_t stream) {
    const float* query      = (const float*)d_in[0];
    const float* qkv_w      = (const float*)d_in[1];
    const float* qkv_b      = (const float*)d_in[2];
    const float* proj_w     = (const float*)d_in[3];
    const float* proj_b     = (const float*)d_in[4];
    const float* bias_table = (const float*)d_in[5];
    // d_in[6] = rel_index (closed-form, unused), d_in[7]=H, d_in[8]=W

    unsigned short* wbf = (unsigned short*)d_ws;              // 2 MiB weights
    unsigned short* xw  = wbf + 1048576;                      // 64 MiB tiled windows
    unsigned short* yw  = xw + 33554432;                      // 64 MiB attention output

    const size_t needA = (size_t)(1048576 + 33554432 + 33554432) * sizeof(unsigned short);
    const size_t needB = (size_t)(1048576 + 33554432) * sizeof(unsigned short);

    if (ws_size >= needA) {
        hipLaunchKernelGGL(wcvt,    dim3(1024),  dim3(256), 0, stream, qkv_w, proj_w, wbf);
        hipLaunchKernelGGL(xcvt,    dim3(16384), dim3(256), 0, stream, query, xw);
        hipLaunchKernelGGL(k_qa,    dim3(4096),  dim3(256), 0, stream,
                           wbf, xw, yw, qkv_b, bias_table);
        hipLaunchKernelGGL(k_proj2, dim3(1024),  dim3(256), 0, stream,
                           wbf, yw, proj_b, (float*)d_out);
    } else if (ws_size >= needB) {
        hipLaunchKernelGGL(wcvt,       dim3(1024),  dim3(256), 0, stream, qkv_w, proj_w, wbf);
        hipLaunchKernelGGL(xcvt,       dim3(16384), dim3(256), 0, stream, query, xw);
        hipLaunchKernelGGL(k_fused_r1, dim3(1024),  dim3(256), 0, stream,
                           wbf, xw, qkv_b, proj_b, bias_table, (float*)d_out);
    }
}

// Round 9
// 419.312 us; speedup vs baseline: 1.3033x; 1.3033x over previous
//
#include <hip/hip_runtime.h>

// ShiftWindowMSA (Swin) fused kernels for MI355X (gfx950).
// B=16, H=W=64, C=512, NH=16, hd=32, WS=8, SS=4 -> 1024 windows x 64 tokens.
//
// R9: revert to the measured champion (R1 monolith path, 409 us) and add ONE
// lever: register-level software pipelining of the L2 operand loads in the
// QKV and proj K-loops (issue iter i+1's A/B loads before iter i's MFMAs).
// Rationale: R1 counters show 65% stall with loads and consuming MFMAs in the
// same iteration; occupancy is LDS-capped at 2 blocks/CU so the +56 VGPR of
// the pipeline is free (256/wave budget at 2 waves/SIMD).
// Evidence ledger: splits falsified (R5 qkvbuf round-trip 280us; R7 total 508);
// (256,3) spills ALWAYS (R2: 84 VGPR catastrophe; R8: VGPR 84 + WRITE 94MB);
// fused-per-window L2 footprint 64win*64KB+2MB > 4MB L2/XCD (R6: 340MB FETCH).
// Fallback (ws < 66 MiB): R0 monolithic k_legacy.

typedef short  short8  __attribute__((ext_vector_type(8)));
typedef short  short4v __attribute__((ext_vector_type(4)));
typedef float  floatx4 __attribute__((ext_vector_type(4)));

#define DEVI static __device__ __forceinline__

DEVI unsigned short f2bf(float f) {
    union { float f; unsigned int u; } v;
    v.f = f;
    return (unsigned short)((v.u + 0x7fffu + ((v.u >> 16) & 1u)) >> 16);
}

// ---------------------------------------------------------------------------
// wcvt: qkv_w (1536x512) then proj_w (512x512) fp32 -> bf16 into wbf.
// ---------------------------------------------------------------------------
__global__ void wcvt(const float* __restrict__ qkv_w,
                     const float* __restrict__ proj_w,
                     unsigned short* __restrict__ wbf) {
    const int idx = ((blockIdx.x << 8) + threadIdx.x) << 2;
    const float* src = (idx < 786432) ? (qkv_w + idx) : (proj_w + (idx - 786432));
    const floatx4 v = *(const floatx4*)src;
    short4v o;
    o[0] = (short)f2bf(v[0]); o[1] = (short)f2bf(v[1]);
    o[2] = (short)f2bf(v[2]); o[3] = (short)f2bf(v[3]);
    *(short4v*)(wbf + idx) = o;
}

// ---------------------------------------------------------------------------
// xcvt: gather cyclic-shifted windows of query -> xw bf16 [win][kc][tok][32].
// ---------------------------------------------------------------------------
__global__ void xcvt(const float* __restrict__ query,
                     unsigned short* __restrict__ xw) {
    const int bid = blockIdx.x;
    const int x   = bid & 7;
    const int s   = bid >> 3;                           // 0..2047
    const int win = (x << 7) + (s >> 4);
    const int rem = ((s & 15) << 8) + threadIdx.x;      // 0..4095
    const int jc  = rem & 3;                            // 8-short chunk in 32
    const int tok = (rem >> 2) & 63;
    const int kc  = rem >> 8;                           // 0..15
    const int b   = win >> 6, wy = (win >> 3) & 7, wx = win & 7;
    const int ty  = tok >> 3, tx = tok & 7;
    const int gh  = ((wy << 3) + ty + 4) & 63;
    const int gw  = ((wx << 3) + tx + 4) & 63;
    const float* src = query + (((b << 12) + (gh << 6) + gw) << 9) + (kc << 5) + (jc << 3);
    const floatx4 v0 = *(const floatx4*)src;
    const floatx4 v1 = *(const floatx4*)(src + 4);
    short8 sv;
    sv[0] = (short)f2bf(v0[0]); sv[1] = (short)f2bf(v0[1]);
    sv[2] = (short)f2bf(v0[2]); sv[3] = (short)f2bf(v0[3]);
    sv[4] = (short)f2bf(v1[0]); sv[5] = (short)f2bf(v1[1]);
    sv[6] = (short)f2bf(v1[2]); sv[7] = (short)f2bf(v1[3]);
    *(short8*)(xw + (win << 15) + (kc << 11) + (tok << 5) + (jc << 3)) = sv;
}

// ---------------------------------------------------------------------------
// k_fused: R1 champion monolith (1 block = 1 window, 4 waves x 4 heads,
// LDS 66560 B -> 2 blocks/CU) with software-pipelined K-loops:
// iter i+1's A/B loads are issued before iter i's MFMA block so the
// compiler's waitcnt lands one iteration back (L2 latency hidden under
// the two co-resident waves' MFMA blocks).
// ---------------------------------------------------------------------------
__global__ __launch_bounds__(256, 2)
void k_fused(const unsigned short* __restrict__ wbf,
             const unsigned short* __restrict__ xw,
             const float* __restrict__ qkv_b,
             const float* __restrict__ proj_b,
             const float* __restrict__ bias_table,
             float* __restrict__ out)
{
    __shared__ __align__(16) unsigned short smem[33280];

    const int tid  = threadIdx.x;
    const int lane = tid & 63;
    const int l15  = lane & 15;
    const int quad = lane >> 4;
    const int wave = tid >> 6;

    const int win = blockIdx.x;
    const int b   = win >> 6;
    const int wy  = (win >> 3) & 7;
    const int wx  = win & 7;
    const int mid = ((wy == 7) ? 2 : 0) | ((wx == 7) ? 1 : 0);

    unsigned short* xs  = smem;
    unsigned short* wb  = smem + wave * 7424;
    unsigned short* qbf = wb;
    unsigned short* kbf = wb + 2560;
    unsigned short* vT  = wb + 5120;
    unsigned short* pbf = wb;

    const unsigned short* xa = xw + (win << 15) + (l15 << 5) + (quad << 3);
    const float scale = 0.17677669529663687f;
    const floatx4 fz = {0.f, 0.f, 0.f, 0.f};
    unsigned int po[4][16];

    for (int hh = 0; hh < 4; ++hh) {
        const int h = (wave << 2) + hh;
        floatx4 accq[4][2], acck[4][2], accv[4][2];
        #pragma unroll
        for (int mt = 0; mt < 4; ++mt)
            #pragma unroll
            for (int nt = 0; nt < 2; ++nt) { accq[mt][nt] = fz; acck[mt][nt] = fz; accv[mt][nt] = fz; }

        const unsigned short* wq = wbf + ((h << 5) + l15) * 512 + (quad << 3);
        const unsigned short* wk = wq + 262144;
        const unsigned short* wv = wk + 262144;

        // ---- software-pipelined QKV K-loop: prologue loads for kk=0 ----
        short8 a_c[4], bq_c[2], bk_c[2], bv_c[2];
        #pragma unroll
        for (int mt = 0; mt < 4; ++mt)
            a_c[mt] = *(const short8*)(xa + (mt << 9));
        #pragma unroll
        for (int nt = 0; nt < 2; ++nt) {
            const int ro = (nt << 4) * 512;
            bq_c[nt] = *(const short8*)(wq + ro);
            bk_c[nt] = *(const short8*)(wk + ro);
            bv_c[nt] = *(const short8*)(wv + ro);
        }
        #pragma unroll 2
        for (int kk = 0; kk < 512; kk += 32) {
            const int kn = (kk + 32) & 511;     // last iter wraps to 0 (L2-hot, harmless)
            short8 a_n[4], bq_n[2], bk_n[2], bv_n[2];
            #pragma unroll
            for (int mt = 0; mt < 4; ++mt)
                a_n[mt] = *(const short8*)(xa + (kn << 6) + (mt << 9));
            #pragma unroll
            for (int nt = 0; nt < 2; ++nt) {
                const int ro = (nt << 4) * 512 + kn;
                bq_n[nt] = *(const short8*)(wq + ro);
                bk_n[nt] = *(const short8*)(wk + ro);
                bv_n[nt] = *(const short8*)(wv + ro);
            }
            #pragma unroll
            for (int nt = 0; nt < 2; ++nt)
                #pragma unroll
                for (int mt = 0; mt < 4; ++mt) {
                    accq[mt][nt] = __builtin_amdgcn_mfma_f32_16x16x32_bf16(a_c[mt], bq_c[nt], accq[mt][nt], 0, 0, 0);
                    acck[mt][nt] = __builtin_amdgcn_mfma_f32_16x16x32_bf16(a_c[mt], bk_c[nt], acck[mt][nt], 0, 0, 0);
                    accv[mt][nt] = __builtin_amdgcn_mfma_f32_16x16x32_bf16(a_c[mt], bv_c[nt], accv[mt][nt], 0, 0, 0);
                }
            #pragma unroll
            for (int mt = 0; mt < 4; ++mt) a_c[mt] = a_n[mt];
            #pragma unroll
            for (int nt = 0; nt < 2; ++nt) {
                bq_c[nt] = bq_n[nt]; bk_c[nt] = bk_n[nt]; bv_c[nt] = bv_n[nt];
            }
        }

        #pragma unroll
        for (int nt = 0; nt < 2; ++nt) {
            const int cix = (h << 5) + (nt << 4) + l15;
            const float bq_ = qkv_b[cix];
            const float bk_ = qkv_b[512 + cix];
            const float bv_ = qkv_b[1024 + cix];
            #pragma unroll
            for (int mt = 0; mt < 4; ++mt) {
                short4v vv;
                #pragma unroll
                for (int r = 0; r < 4; ++r) {
                    const int row = (mt << 4) + (quad << 2) + r;
                    qbf[row * 40 + (nt << 4) + l15] = f2bf(accq[mt][nt][r] + bq_);
                    kbf[row * 40 + (nt << 4) + l15] = f2bf(acck[mt][nt][r] + bk_);
                    vv[r] = (short)f2bf(accv[mt][nt][r] + bv_);
                }
                *(short4v*)&vT[((nt << 4) + l15) * 72 + (mt << 4) + (quad << 2)] = vv;
            }
        }

        short8 qa[4], ka[4];
        #pragma unroll
        for (int t = 0; t < 4; ++t) {
            qa[t] = *(const short8*)&qbf[((t << 4) + l15) * 40 + (quad << 3)];
            ka[t] = *(const short8*)&kbf[((t << 4) + l15) * 40 + (quad << 3)];
        }
        floatx4 s4[4][4];
        #pragma unroll
        for (int mt = 0; mt < 4; ++mt)
            #pragma unroll
            for (int nt = 0; nt < 4; ++nt)
                s4[mt][nt] = __builtin_amdgcn_mfma_f32_16x16x32_bf16(qa[mt], ka[nt], fz, 0, 0, 0);

        int  gjv[4]; bool jrow[4], jcol[4];
        #pragma unroll
        for (int nt = 0; nt < 4; ++nt) {
            const int j  = (nt << 4) + l15;
            const int j2 = 63 - j;
            gjv[nt]  = 15 * (j2 >> 3) + (j2 & 7);
            jrow[nt] = (j >> 3) < 4;
            jcol[nt] = (j & 7) < 4;
        }
        #pragma unroll
        for (int mt = 0; mt < 4; ++mt) {
            const int i0  = (mt << 4) + (quad << 2);
            const int fi0 = 15 * (i0 >> 3) + (i0 & 7);
            const bool irow = (i0 >> 3) < 4;
            const bool icol = (i0 & 7) == 0;
            #pragma unroll
            for (int nt = 0; nt < 4; ++nt) {
                float mval = 0.0f;
                if ((mid & 2) && (irow != jrow[nt])) mval = -100.0f;
                if ((mid & 1) && (icol != jcol[nt])) mval = -100.0f;
                const float* bp = bias_table + (fi0 + gjv[nt]) * 16 + h;
                #pragma unroll
                for (int r = 0; r < 4; ++r)
                    s4[mt][nt][r] = s4[mt][nt][r] * scale + bp[r * 16] + mval;
            }
        }

        #pragma unroll
        for (int mt = 0; mt < 4; ++mt)
            #pragma unroll
            for (int r = 0; r < 4; ++r) {
                float m = fmaxf(fmaxf(s4[mt][0][r], s4[mt][1][r]),
                                fmaxf(s4[mt][2][r], s4[mt][3][r]));
                m = fmaxf(m, __shfl_xor(m, 1));
                m = fmaxf(m, __shfl_xor(m, 2));
                m = fmaxf(m, __shfl_xor(m, 4));
                m = fmaxf(m, __shfl_xor(m, 8));
                float loc = 0.0f;
                #pragma unroll
                for (int nt = 0; nt < 4; ++nt) {
                    s4[mt][nt][r] = __expf(s4[mt][nt][r] - m);
                    loc += s4[mt][nt][r];
                }
                loc += __shfl_xor(loc, 1);
                loc += __shfl_xor(loc, 2);
                loc += __shfl_xor(loc, 4);
                loc += __shfl_xor(loc, 8);
                const float inv = 1.0f / loc;
                const int row = (mt << 4) + (quad << 2) + r;
                #pragma unroll
                for (int nt = 0; nt < 4; ++nt)
                    pbf[row * 72 + (nt << 4) + l15] = f2bf(s4[mt][nt][r] * inv);
            }

        short8 pa[4][2], va[2][2];
        #pragma unroll
        for (int mt = 0; mt < 4; ++mt)
            #pragma unroll
            for (int ks = 0; ks < 2; ++ks)
                pa[mt][ks] = *(const short8*)&pbf[((mt << 4) + l15) * 72 + (ks << 5) + (quad << 3)];
        #pragma unroll
        for (int nt = 0; nt < 2; ++nt)
            #pragma unroll
            for (int ks = 0; ks < 2; ++ks)
                va[nt][ks] = *(const short8*)&vT[((nt << 4) + l15) * 72 + (ks << 5) + (quad << 3)];

        #pragma unroll
        for (int mt = 0; mt < 4; ++mt)
            #pragma unroll
            for (int nt = 0; nt < 2; ++nt) {
                floatx4 acc = fz;
                acc = __builtin_amdgcn_mfma_f32_16x16x32_bf16(pa[mt][0], va[nt][0], acc, 0, 0, 0);
                acc = __builtin_amdgcn_mfma_f32_16x16x32_bf16(pa[mt][1], va[nt][1], acc, 0, 0, 0);
                const int pi = ((mt << 1) + nt) << 1;
                po[hh][pi]     = (unsigned int)f2bf(acc[0]) | ((unsigned int)f2bf(acc[1]) << 16);
                po[hh][pi + 1] = (unsigned int)f2bf(acc[2]) | ((unsigned int)f2bf(acc[3]) << 16);
            }
    }
    __syncthreads();

    #pragma unroll
    for (int hh = 0; hh < 4; ++hh) {
        const int ch0 = (((wave << 2) + hh) << 5) + l15;
        #pragma unroll
        for (int mt = 0; mt < 4; ++mt)
            #pragma unroll
            for (int nt = 0; nt < 2; ++nt) {
                const int pi = ((mt << 1) + nt) << 1;
                #pragma unroll
                for (int r = 0; r < 4; ++r) {
                    const int row = (mt << 4) + (quad << 2) + r;
                    const unsigned int w = po[hh][pi + (r >> 1)];
                    xs[row * 520 + ch0 + (nt << 4)] =
                        (unsigned short)((w >> ((r & 1) << 4)) & 0xffffu);
                }
            }
    }
    __syncthreads();

    // ---------------- proj GEMM with B-prefetch pipeline ---------------------
    const unsigned short* pwb = wbf + 786432;
    for (int pass = 0; pass < 2; ++pass) {
        const int co0 = (wave << 7) + (pass << 6);
        floatx4 acc[4][4];
        #pragma unroll
        for (int mt = 0; mt < 4; ++mt)
            #pragma unroll
            for (int nt = 0; nt < 4; ++nt) acc[mt][nt] = fz;

        const unsigned short* wp = pwb + (co0 + l15) * 512 + (quad << 3);

        short8 bf_c[4];
        #pragma unroll
        for (int nt = 0; nt < 4; ++nt)
            bf_c[nt] = *(const short8*)(wp + (nt << 4) * 512);

        #pragma unroll 2
        for (int kk = 0; kk < 512; kk += 32) {
            const int kn = (kk + 32) & 511;
            short8 a[4], bf_n[4];
            #pragma unroll
            for (int nt = 0; nt < 4; ++nt)
                bf_n[nt] = *(const short8*)(wp + (nt << 4) * 512 + kn);
            #pragma unroll
            for (int mt = 0; mt < 4; ++mt)
                a[mt] = *(const short8*)&xs[((mt << 4) + l15) * 520 + kk + (quad << 3)];
            #pragma unroll
            for (int nt = 0; nt < 4; ++nt)
                #pragma unroll
                for (int mt = 0; mt < 4; ++mt)
                    acc[mt][nt] = __builtin_amdgcn_mfma_f32_16x16x32_bf16(a[mt], bf_c[nt], acc[mt][nt], 0, 0, 0);
            #pragma unroll
            for (int nt = 0; nt < 4; ++nt) bf_c[nt] = bf_n[nt];
        }

        #pragma unroll
        for (int nt = 0; nt < 4; ++nt) {
            const float pb_ = proj_b[co0 + (nt << 4) + l15];
            #pragma unroll
            for (int mt = 0; mt < 4; ++mt)
                #pragma unroll
                for (int r = 0; r < 4; ++r) {
                    const int tok = (mt << 4) + (quad << 2) + r;
                    const int ty = tok >> 3, tx = tok & 7;
                    const int gh = ((wy << 3) + ty + 4) & 63;
                    const int gw = ((wx << 3) + tx + 4) & 63;
                    out[(((b << 12) + (gh << 6) + gw) << 9) + co0 + (nt << 4) + l15] =
                        acc[mt][nt][r] + pb_;
                }
        }
    }
}

// ---------------------------------------------------------------------------
// Fallback (ws < 66 MiB): R0 monolithic kernel (stages window in LDS).
// ---------------------------------------------------------------------------
__global__ __launch_bounds__(256, 1)
void k_legacy(const float* __restrict__ query,
              const unsigned short* __restrict__ wbf,
              const float* __restrict__ qkv_b,
              const float* __restrict__ proj_b,
              const float* __restrict__ bias_table,
              float* __restrict__ out)
{
    __shared__ __align__(16) unsigned short smem[62976];

    const int tid  = threadIdx.x;
    const int lane = tid & 63;
    const int l15  = lane & 15;
    const int quad = lane >> 4;
    const int wave = tid >> 6;

    const int win = blockIdx.x;
    const int b   = win >> 6;
    const int wy  = (win >> 3) & 7;
    const int wx  = win & 7;
    const int mid = ((wy == 7) ? 2 : 0) | ((wx == 7) ? 1 : 0);

    unsigned short* xs  = smem;
    unsigned short* wb  = smem + 33280 + wave * 7424;
    unsigned short* qbf = wb;
    unsigned short* kbf = wb + 2560;
    unsigned short* vT  = wb + 5120;
    unsigned short* pbf = wb;

    #pragma unroll
    for (int it = 0; it < 32; ++it) {
        const int c   = tid + (it << 8);
        const int tok = c >> 7;
        const int fo  = (c & 127) << 2;
        const int ty  = tok >> 3, tx = tok & 7;
        const int gh  = ((wy << 3) + ty + 4) & 63;
        const int gw  = ((wx << 3) + tx + 4) & 63;
        const floatx4 v = *(const floatx4*)(query + (((b << 12) + (gh << 6) + gw) << 9) + fo);
        short4v s;
        s[0] = (short)f2bf(v[0]); s[1] = (short)f2bf(v[1]);
        s[2] = (short)f2bf(v[2]); s[3] = (short)f2bf(v[3]);
        *(short4v*)&xs[tok * 520 + fo] = s;
    }
    __syncthreads();

    const float scale = 0.17677669529663687f;
    const floatx4 fz = {0.f, 0.f, 0.f, 0.f};
    unsigned int po[4][16];

    for (int hh = 0; hh < 4; ++hh) {
        const int h = (wave << 2) + hh;
        floatx4 accq[4][2], acck[4][2], accv[4][2];
        #pragma unroll
        for (int mt = 0; mt < 4; ++mt)
            #pragma unroll
            for (int nt = 0; nt < 2; ++nt) { accq[mt][nt] = fz; acck[mt][nt] = fz; accv[mt][nt] = fz; }

        const unsigned short* wq = wbf + ((h << 5) + l15) * 512 + (quad << 3);
        const unsigned short* wk = wq + 262144;
        const unsigned short* wv = wk + 262144;

        #pragma unroll 2
        for (int kk = 0; kk < 512; kk += 32) {
            short8 a[4], bq[2], bk2[2], bv2[2];
            #pragma unroll
            for (int mt = 0; mt < 4; ++mt)
                a[mt] = *(const short8*)&xs[((mt << 4) + l15) * 520 + kk + (quad << 3)];
            #pragma unroll
            for (int nt = 0; nt < 2; ++nt) {
                const int ro = (nt << 4) * 512 + kk;
                bq[nt]  = *(const short8*)(wq + ro);
                bk2[nt] = *(const short8*)(wk + ro);
                bv2[nt] = *(const short8*)(wv + ro);
            }
            #pragma unroll
            for (int nt = 0; nt < 2; ++nt)
                #pragma unroll
                for (int mt = 0; mt < 4; ++mt) {
                    accq[mt][nt] = __builtin_amdgcn_mfma_f32_16x16x32_bf16(a[mt], bq[nt],  accq[mt][nt], 0, 0, 0);
                    acck[mt][nt] = __builtin_amdgcn_mfma_f32_16x16x32_bf16(a[mt], bk2[nt], acck[mt][nt], 0, 0, 0);
                    accv[mt][nt] = __builtin_amdgcn_mfma_f32_16x16x32_bf16(a[mt], bv2[nt], accv[mt][nt], 0, 0, 0);
                }
        }

        #pragma unroll
        for (int nt = 0; nt < 2; ++nt) {
            const int cix = (h << 5) + (nt << 4) + l15;
            const float bq_ = qkv_b[cix];
            const float bk_ = qkv_b[512 + cix];
            const float bv_ = qkv_b[1024 + cix];
            #pragma unroll
            for (int mt = 0; mt < 4; ++mt) {
                short4v vv;
                #pragma unroll
                for (int r = 0; r < 4; ++r) {
                    const int row = (mt << 4) + (quad << 2) + r;
                    qbf[row * 40 + (nt << 4) + l15] = f2bf(accq[mt][nt][r] + bq_);
                    kbf[row * 40 + (nt << 4) + l15] = f2bf(acck[mt][nt][r] + bk_);
                    vv[r] = (short)f2bf(accv[mt][nt][r] + bv_);
                }
                *(short4v*)&vT[((nt << 4) + l15) * 72 + (mt << 4) + (quad << 2)] = vv;
            }
        }

        short8 qa[4], ka[4];
        #pragma unroll
        for (int t = 0; t < 4; ++t) {
            qa[t] = *(const short8*)&qbf[((t << 4) + l15) * 40 + (quad << 3)];
            ka[t] = *(const short8*)&kbf[((t << 4) + l15) * 40 + (quad << 3)];
        }
        floatx4 s4[4][4];
        #pragma unroll
        for (int mt = 0; mt < 4; ++mt)
            #pragma unroll
            for (int nt = 0; nt < 4; ++nt)
                s4[mt][nt] = __builtin_amdgcn_mfma_f32_16x16x32_bf16(qa[mt], ka[nt], fz, 0, 0, 0);

        int  gjv[4]; bool jrow[4], jcol[4];
        #pragma unroll
        for (int nt = 0; nt < 4; ++nt) {
            const int j  = (nt << 4) + l15;
            const int j2 = 63 - j;
            gjv[nt]  = 15 * (j2 >> 3) + (j2 & 7);
            jrow[nt] = (j >> 3) < 4;
            jcol[nt] = (j & 7) < 4;
        }
        #pragma unroll
        for (int mt = 0; mt < 4; ++mt) {
            const int i0  = (mt << 4) + (quad << 2);
            const int fi0 = 15 * (i0 >> 3) + (i0 & 7);
            const bool irow = (i0 >> 3) < 4;
            const bool icol = (i0 & 7) == 0;
            #pragma unroll
            for (int nt = 0; nt < 4; ++nt) {
                float mval = 0.0f;
                if ((mid & 2) && (irow != jrow[nt])) mval = -100.0f;
                if ((mid & 1) && (icol != jcol[nt])) mval = -100.0f;
                const float* bp = bias_table + (fi0 + gjv[nt]) * 16 + h;
                #pragma unroll
                for (int r = 0; r < 4; ++r)
                    s4[mt][nt][r] = s4[mt][nt][r] * scale + bp[r * 16] + mval;
            }
        }

        #pragma unroll
        for (int mt = 0; mt < 4; ++mt)
            #pragma unroll
            for (int r = 0; r < 4; ++r) {
                float m = fmaxf(fmaxf(s4[mt][0][r], s4[mt][1][r]),
                                fmaxf(s4[mt][2][r], s4[mt][3][r]));
                m = fmaxf(m, __shfl_xor(m, 1));
                m = fmaxf(m, __shfl_xor(m, 2));
                m = fmaxf(m, __shfl_xor(m, 4));
                m = fmaxf(m, __shfl_xor(m, 8));
                float loc = 0.0f;
                #pragma unroll
                for (int nt = 0; nt < 4; ++nt) {
                    s4[mt][nt][r] = __expf(s4[mt][nt][r] - m);
                    loc += s4[mt][nt][r];
                }
                loc += __shfl_xor(loc, 1);
                loc += __shfl_xor(loc, 2);
                loc += __shfl_xor(loc, 4);
                loc += __shfl_xor(loc, 8);
                const float inv = 1.0f / loc;
                const int row = (mt << 4) + (quad << 2) + r;
                #pragma unroll
                for (int nt = 0; nt < 4; ++nt)
                    pbf[row * 72 + (nt << 4) + l15] = f2bf(s4[mt][nt][r] * inv);
            }

        short8 pa[4][2], va[2][2];
        #pragma unroll
        for (int mt = 0; mt < 4; ++mt)
            #pragma unroll
            for (int ks = 0; ks < 2; ++ks)
                pa[mt][ks] = *(const short8*)&pbf[((mt << 4) + l15) * 72 + (ks << 5) + (quad << 3)];
        #pragma unroll
        for (int nt = 0; nt < 2; ++nt)
            #pragma unroll
            for (int ks = 0; ks < 2; ++ks)
                va[nt][ks] = *(const short8*)&vT[((nt << 4) + l15) * 72 + (ks << 5) + (quad << 3)];

        #pragma unroll
        for (int mt = 0; mt < 4; ++mt)
            #pragma unroll
            for (int nt = 0; nt < 2; ++nt) {
                floatx4 acc = fz;
                acc = __builtin_amdgcn_mfma_f32_16x16x32_bf16(pa[mt][0], va[nt][0], acc, 0, 0, 0);
                acc = __builtin_amdgcn_mfma_f32_16x16x32_bf16(pa[mt][1], va[nt][1], acc, 0, 0, 0);
                const int pi = ((mt << 1) + nt) << 1;
                po[hh][pi]     = (unsigned int)f2bf(acc[0]) | ((unsigned int)f2bf(acc[1]) << 16);
                po[hh][pi + 1] = (unsigned int)f2bf(acc[2]) | ((unsigned int)f2bf(acc[3]) << 16);
            }
    }
    __syncthreads();

    #pragma unroll
    for (int hh = 0; hh < 4; ++hh) {
        const int ch0 = (((wave << 2) + hh) << 5) + l15;
        #pragma unroll
        for (int mt = 0; mt < 4; ++mt)
            #pragma unroll
            for (int nt = 0; nt < 2; ++nt) {
                const int pi = ((mt << 1) + nt) << 1;
                #pragma unroll
                for (int r = 0; r < 4; ++r) {
                    const int row = (mt << 4) + (quad << 2) + r;
                    const unsigned int w = po[hh][pi + (r >> 1)];
                    xs[row * 520 + ch0 + (nt << 4)] =
                        (unsigned short)((w >> ((r & 1) << 4)) & 0xffffu);
                }
            }
    }
    __syncthreads();

    const unsigned short* pwb = wbf + 786432;
    for (int pass = 0; pass < 2; ++pass) {
        const int co0 = (wave << 7) + (pass << 6);
        floatx4 acc[4][4];
        #pragma unroll
        for (int mt = 0; mt < 4; ++mt)
            #pragma unroll
            for (int nt = 0; nt < 4; ++nt) acc[mt][nt] = fz;

        const unsigned short* wp = pwb + (co0 + l15) * 512 + (quad << 3);

        #pragma unroll 2
        for (int kk = 0; kk < 512; kk += 32) {
            short8 a[4], bfr[4];
            #pragma unroll
            for (int mt = 0; mt < 4; ++mt)
                a[mt] = *(const short8*)&xs[((mt << 4) + l15) * 520 + kk + (quad << 3)];
            #pragma unroll
            for (int nt = 0; nt < 4; ++nt)
                bfr[nt] = *(const short8*)(wp + (nt << 4) * 512 + kk);
            #pragma unroll
            for (int nt = 0; nt < 4; ++nt)
                #pragma unroll
                for (int mt = 0; mt < 4; ++mt)
                    acc[mt][nt] = __builtin_amdgcn_mfma_f32_16x16x32_bf16(a[mt], bfr[nt], acc[mt][nt], 0, 0, 0);
        }

        #pragma unroll
        for (int nt = 0; nt < 4; ++nt) {
            const float pb_ = proj_b[co0 + (nt << 4) + l15];
            #pragma unroll
            for (int mt = 0; mt < 4; ++mt)
                #pragma unroll
                for (int r = 0; r < 4; ++r) {
                    const int tok = (mt << 4) + (quad << 2) + r;
                    const int ty = tok >> 3, tx = tok & 7;
                    const int gh = ((wy << 3) + ty + 4) & 63;
                    const int gw = ((wx << 3) + tx + 4) & 63;
                    out[(((b << 12) + (gh << 6) + gw) << 9) + co0 + (nt << 4) + l15] =
                        acc[mt][nt][r] + pb_;
                }
        }
    }
}

// ---------------------------------------------------------------------------
extern "C" void kernel_launch(void* const* d_in, const int* in_sizes, int n_in,
                              void* d_out, int out_size, void* d_ws, size_t ws_size,
                              hipStream_t stream) {
    const float* query      = (const float*)d_in[0];
    const float* qkv_w      = (const float*)d_in[1];
    const float* qkv_b      = (const float*)d_in[2];
    const float* proj_w     = (const float*)d_in[3];
    const float* proj_b     = (const float*)d_in[4];
    const float* bias_table = (const float*)d_in[5];
    // d_in[6] = rel_index (closed-form, unused), d_in[7]=H, d_in[8]=W

    unsigned short* wbf = (unsigned short*)d_ws;              // 2 MiB weights
    unsigned short* xw  = wbf + 1048576;                      // 64 MiB tiled windows

    const size_t needB = (size_t)(1048576 + 33554432) * sizeof(unsigned short);

    if (ws_size >= needB) {
        hipLaunchKernelGGL(wcvt,    dim3(1024),  dim3(256), 0, stream, qkv_w, proj_w, wbf);
        hipLaunchKernelGGL(xcvt,    dim3(16384), dim3(256), 0, stream, query, xw);
        hipLaunchKernelGGL(k_fused, dim3(1024),  dim3(256), 0, stream,
                           wbf, xw, qkv_b, proj_b, bias_table, (float*)d_out);
    } else {
        hipLaunchKernelGGL(wcvt,     dim3(1024), dim3(256), 0, stream, qkv_w, proj_w, wbf);
        hipLaunchKernelGGL(k_legacy, dim3(1024), dim3(256), 0, stream,
                           query, wbf, qkv_b, proj_b, bias_table, (float*)d_out);
    }
}